// Round 1
// baseline (417.799 us; speedup 1.0000x reference)
//
#include <hip/hip_runtime.h>

typedef __bf16 bf16x8 __attribute__((ext_vector_type(8)));
typedef float f32x4 __attribute__((ext_vector_type(4)));
typedef unsigned short u16;
typedef u16 u16x8 __attribute__((ext_vector_type(8)));

__device__ __forceinline__ u16 f2bf(float f) {
  unsigned u = __builtin_bit_cast(unsigned, f);
  unsigned r = (u + 0x7fffu + ((u >> 16) & 1u)) >> 16;  // RNE
  return (u16)r;
}

// ---------------------------------------------------------------------------
// Kernel 1: L[n,c,d] = scale * sum_s K[n,c,s] * Q[n,d,s]
// BM=128 (c), BN=64 (d), BK=64. 256 threads = 4 waves (2x2), wave tile 64x32.
// ---------------------------------------------------------------------------
__global__ __launch_bounds__(256) void k_sim(const float* __restrict__ K,
                                             const float* __restrict__ Q,
                                             float* __restrict__ L) {
  __shared__ u16 sA[128 * 64];
  __shared__ u16 sB[64 * 64];
  const int n = blockIdx.z;
  const int c0 = blockIdx.y * 128;
  const int d0 = blockIdx.x * 64;
  const int t = threadIdx.x;
  const int lane = t & 63, wid = t >> 6;
  const int wr = wid >> 1, wc = wid & 1;
  const float scale = 0.04419417382415922f;  // 512^-0.5

  f32x4 acc[4][2] = {};
  const float* Kb = K + ((size_t)n * 512 + c0) * 4096;
  const float* Qb = Q + ((size_t)n * 512 + d0) * 4096;

  for (int k0 = 0; k0 < 4096; k0 += 64) {
    // stage A tile (128x64) fp32 -> bf16, swizzled LDS
#pragma unroll
    for (int p = 0; p < 4; ++p) {
      int chunk = p * 256 + t;
      int row = chunk >> 3, col = (chunk & 7) << 3;
      const float* src = Kb + (size_t)row * 4096 + k0 + col;
      float4 v0 = *(const float4*)src;
      float4 v1 = *(const float4*)(src + 4);
      bf16x8 h;
      h[0] = (__bf16)v0.x; h[1] = (__bf16)v0.y; h[2] = (__bf16)v0.z; h[3] = (__bf16)v0.w;
      h[4] = (__bf16)v1.x; h[5] = (__bf16)v1.y; h[6] = (__bf16)v1.z; h[7] = (__bf16)v1.w;
      int hw = (row * 64 + col) ^ ((row & 7) << 3);
      *(bf16x8*)(&sA[hw]) = h;
    }
    // stage B tile (64x64)
#pragma unroll
    for (int p = 0; p < 2; ++p) {
      int chunk = p * 256 + t;
      int row = chunk >> 3, col = (chunk & 7) << 3;
      const float* src = Qb + (size_t)row * 4096 + k0 + col;
      float4 v0 = *(const float4*)src;
      float4 v1 = *(const float4*)(src + 4);
      bf16x8 h;
      h[0] = (__bf16)v0.x; h[1] = (__bf16)v0.y; h[2] = (__bf16)v0.z; h[3] = (__bf16)v0.w;
      h[4] = (__bf16)v1.x; h[5] = (__bf16)v1.y; h[6] = (__bf16)v1.z; h[7] = (__bf16)v1.w;
      int hw = (row * 64 + col) ^ ((row & 7) << 3);
      *(bf16x8*)(&sB[hw]) = h;
    }
    __syncthreads();
#pragma unroll
    for (int ki = 0; ki < 2; ++ki) {
      bf16x8 a[4], b[2];
#pragma unroll
      for (int mi = 0; mi < 4; ++mi) {
        int row = wr * 64 + mi * 16 + (lane & 15);
        int hw = (row * 64 + ki * 32 + (lane >> 4) * 8) ^ ((row & 7) << 3);
        a[mi] = *(const bf16x8*)(&sA[hw]);
      }
#pragma unroll
      for (int ni = 0; ni < 2; ++ni) {
        int row = wc * 32 + ni * 16 + (lane & 15);
        int hw = (row * 64 + ki * 32 + (lane >> 4) * 8) ^ ((row & 7) << 3);
        b[ni] = *(const bf16x8*)(&sB[hw]);
      }
#pragma unroll
      for (int mi = 0; mi < 4; ++mi)
#pragma unroll
        for (int ni = 0; ni < 2; ++ni)
          acc[mi][ni] = __builtin_amdgcn_mfma_f32_16x16x32_bf16(a[mi], b[ni], acc[mi][ni], 0, 0, 0);
    }
    __syncthreads();
  }
  float* Lb = L + (size_t)n * 512 * 512;
#pragma unroll
  for (int mi = 0; mi < 4; ++mi)
#pragma unroll
    for (int ni = 0; ni < 2; ++ni) {
      int colo = d0 + wc * 32 + ni * 16 + (lane & 15);
#pragma unroll
      for (int j = 0; j < 4; ++j) {
        int rowo = c0 + wr * 64 + mi * 16 + ((lane >> 4) << 2) + j;
        Lb[(size_t)rowo * 512 + colo] = acc[mi][ni][j] * scale;
      }
    }
}

// ---------------------------------------------------------------------------
// Kernel 2: per (n,d) column softmax over c; materialize E=exp(L-m)/s in bf16
// ---------------------------------------------------------------------------
__global__ __launch_bounds__(256) void k_stats(const float* __restrict__ L,
                                               u16* __restrict__ E) {
  const int n = blockIdx.y;
  const int d = blockIdx.x * 256 + threadIdx.x;
  const float* Lb = L + (size_t)n * 512 * 512 + d;
  float m = -3.0e38f;
  for (int c = 0; c < 512; ++c) m = fmaxf(m, Lb[(size_t)c * 512]);
  float s = 0.f;
  for (int c = 0; c < 512; ++c) s += __expf(Lb[(size_t)c * 512] - m);
  float si = 1.0f / s;
  u16* Eb = E + (size_t)n * 512 * 512 + d;
  for (int c = 0; c < 512; ++c)
    Eb[(size_t)c * 512] = f2bf(__expf(Lb[(size_t)c * 512] - m) * si);
}

// ---------------------------------------------------------------------------
// Kernel 3: Vt[n,s,d] = bf16(V[n,d,s])  (64x64 LDS tile transpose)
// ---------------------------------------------------------------------------
__global__ __launch_bounds__(256) void k_vt(const float* __restrict__ V,
                                            u16* __restrict__ Vt) {
  __shared__ float ldsT[64 * 68];
  const int n = blockIdx.z, d0 = blockIdx.y * 64, s0 = blockIdx.x * 64;
  const int t = threadIdx.x;
  {
    int c4 = t & 15, r0 = t >> 4;
#pragma unroll
    for (int p = 0; p < 4; ++p) {
      int r = r0 + p * 16;
      float4 v = *(const float4*)(V + ((size_t)n * 512 + d0 + r) * 4096 + s0 + c4 * 4);
      *(float4*)(&ldsT[r * 68 + c4 * 4]) = v;
    }
  }
  __syncthreads();
  {
    int sr = t >> 2, part = t & 3;
    u16x8 u0, u1;
#pragma unroll
    for (int i = 0; i < 8; ++i) u0[i] = f2bf(ldsT[(part * 16 + i) * 68 + sr]);
#pragma unroll
    for (int i = 0; i < 8; ++i) u1[i] = f2bf(ldsT[(part * 16 + 8 + i) * 68 + sr]);
    u16* dst = Vt + ((size_t)n * 4096 + s0 + sr) * 512 + d0 + part * 16;
    *(u16x8*)dst = u0;
    *(u16x8*)(dst + 8) = u1;
  }
}

// ---------------------------------------------------------------------------
// Kernel 4: out[n,c,s] = sum_d E[n,c,d] * Vt[n,s,d]
// BM=128 (c), BN=128 (s), BK=64. 4 waves 2x2, wave tile 64x64.
// ---------------------------------------------------------------------------
__global__ __launch_bounds__(256) void k_ctx(const u16* __restrict__ E,
                                             const u16* __restrict__ Vt,
                                             float* __restrict__ O) {
  __shared__ u16 sA[128 * 64];
  __shared__ u16 sB[128 * 64];
  const int n = blockIdx.z;
  const int c0 = blockIdx.y * 128;
  const int s0 = blockIdx.x * 128;
  const int t = threadIdx.x, lane = t & 63, wid = t >> 6;
  const int wr = wid >> 1, wc = wid & 1;
  f32x4 acc[4][4] = {};
  const u16* Eb = E + ((size_t)n * 512 + c0) * 512;
  const u16* Vb = Vt + ((size_t)n * 4096 + s0) * 512;

  for (int kd = 0; kd < 512; kd += 64) {
#pragma unroll
    for (int p = 0; p < 4; ++p) {
      int chunk = p * 256 + t;
      int row = chunk >> 3, col = (chunk & 7) << 3;
      u16x8 hA = *(const u16x8*)(Eb + (size_t)row * 512 + kd + col);
      u16x8 hB = *(const u16x8*)(Vb + (size_t)row * 512 + kd + col);
      int hw = (row * 64 + col) ^ ((row & 7) << 3);
      *(u16x8*)(&sA[hw]) = hA;
      *(u16x8*)(&sB[hw]) = hB;
    }
    __syncthreads();
#pragma unroll
    for (int ki = 0; ki < 2; ++ki) {
      bf16x8 a[4], b[4];
#pragma unroll
      for (int mi = 0; mi < 4; ++mi) {
        int row = wr * 64 + mi * 16 + (lane & 15);
        int hw = (row * 64 + ki * 32 + (lane >> 4) * 8) ^ ((row & 7) << 3);
        a[mi] = *(const bf16x8*)(&sA[hw]);
      }
#pragma unroll
      for (int ni = 0; ni < 4; ++ni) {
        int row = wc * 64 + ni * 16 + (lane & 15);
        int hw = (row * 64 + ki * 32 + (lane >> 4) * 8) ^ ((row & 7) << 3);
        b[ni] = *(const bf16x8*)(&sB[hw]);
      }
#pragma unroll
      for (int mi = 0; mi < 4; ++mi)
#pragma unroll
        for (int ni = 0; ni < 4; ++ni)
          acc[mi][ni] = __builtin_amdgcn_mfma_f32_16x16x32_bf16(a[mi], b[ni], acc[mi][ni], 0, 0, 0);
    }
    __syncthreads();
  }
  float* Ob = O + ((size_t)n * 512 + c0) * 4096 + s0;
#pragma unroll
  for (int mi = 0; mi < 4; ++mi)
#pragma unroll
    for (int ni = 0; ni < 4; ++ni) {
      int colo = wc * 64 + ni * 16 + (lane & 15);
#pragma unroll
      for (int j = 0; j < 4; ++j) {
        int rowo = wr * 64 + mi * 16 + ((lane >> 4) << 2) + j;
        Ob[(size_t)rowo * 4096 + colo] = acc[mi][ni][j];
      }
    }
}

extern "C" void kernel_launch(void* const* d_in, const int* in_sizes, int n_in,
                              void* d_out, int out_size, void* d_ws, size_t ws_size,
                              hipStream_t stream) {
  const float* Kp = (const float*)d_in[0];  // key
  const float* Vp = (const float*)d_in[1];  // value
  const float* Qp = (const float*)d_in[2];  // query
  float* Op = (float*)d_out;

  const size_t L_BYTES = (size_t)16 * 512 * 512 * 4;   // 16 MiB
  const size_t E_BYTES = (size_t)16 * 512 * 512 * 2;   //  8 MiB
  const size_t VT_BYTES = (size_t)16 * 4096 * 512 * 2; // 64 MiB
  if (ws_size < L_BYTES + E_BYTES + VT_BYTES) return;  // insufficient scratch

  char* ws = (char*)d_ws;
  float* L = (float*)ws;
  u16* E = (u16*)(ws + L_BYTES);
  u16* Vt = (u16*)(ws + L_BYTES + E_BYTES);

  k_sim<<<dim3(8, 4, 16), 256, 0, stream>>>(Kp, Qp, L);
  k_stats<<<dim3(2, 16), 256, 0, stream>>>(L, E);
  k_vt<<<dim3(64, 8, 16), 256, 0, stream>>>(Vp, Vt);
  k_ctx<<<dim3(32, 4, 16), 256, 0, stream>>>(E, Vt, Op);
}

// Round 2
// 399.097 us; speedup vs baseline: 1.0469x; 1.0469x over previous
//
#include <hip/hip_runtime.h>

typedef __bf16 bf16x8 __attribute__((ext_vector_type(8)));
typedef float f32x4 __attribute__((ext_vector_type(4)));
typedef unsigned short u16;
typedef u16 u16x8 __attribute__((ext_vector_type(8)));

__device__ __forceinline__ u16 f2bf(float f) {
  unsigned u = __builtin_bit_cast(unsigned, f);
  unsigned r = (u + 0x7fffu + ((u >> 16) & 1u)) >> 16;  // RNE
  return (u16)r;
}

// async global->LDS, 16B per lane. LDS dest must be wave-uniform base (+lane*16 HW).
__device__ __forceinline__ void gld_lds16(const u16* g, u16* l) {
  __builtin_amdgcn_global_load_lds(
      (__attribute__((address_space(1))) void*)(g),
      (__attribute__((address_space(3))) void*)(l), 16, 0, 0);
}

// ---------------------------------------------------------------------------
// k_cvt: fp32 -> bf16 straight cast for K (y=0) and Q (y=1). 33.5M elems each.
// ---------------------------------------------------------------------------
__global__ __launch_bounds__(256) void k_cvt(const float* __restrict__ K,
                                             const float* __restrict__ Q,
                                             u16* __restrict__ Kb,
                                             u16* __restrict__ Qb) {
  const float* src = blockIdx.y ? Q : K;
  u16* dst = blockIdx.y ? Qb : Kb;
  const size_t total = (size_t)16 * 512 * 4096;
  size_t i = ((size_t)blockIdx.x * 256 + threadIdx.x) * 8;
  const size_t stride = (size_t)gridDim.x * 256 * 8;
  for (; i < total; i += stride) {
    float4 a = *(const float4*)(src + i);
    float4 b = *(const float4*)(src + i + 4);
    u16x8 h;
    h[0] = f2bf(a.x); h[1] = f2bf(a.y); h[2] = f2bf(a.z); h[3] = f2bf(a.w);
    h[4] = f2bf(b.x); h[5] = f2bf(b.y); h[6] = f2bf(b.z); h[7] = f2bf(b.w);
    *(u16x8*)(dst + i) = h;
  }
}

// ---------------------------------------------------------------------------
// k_sim2: L[n,c,d] = scale * sum_s Kb[n,c,s]*Qb[n,d,s]  (bf16 in, fp32 out)
// m97 structure: 128x128 tile, BK=64, 256 thr / 4 waves (2x2, wave 64x64),
// global_load_lds width-16 staging into LINEAR LDS. 256 blocks, XCD swizzle.
// ---------------------------------------------------------------------------
__global__ __launch_bounds__(256) void k_sim2(const u16* __restrict__ Kb,
                                              const u16* __restrict__ Qb,
                                              float* __restrict__ L) {
  __shared__ u16 sA[128 * 64];
  __shared__ u16 sB[128 * 64];
  const int bid = blockIdx.x;
  const int sid = (bid & 7) * 32 + (bid >> 3);  // 256 blocks -> batch-per-XCD locality
  const int n = sid >> 4;
  const int cy = (sid >> 2) & 3, dx = sid & 3;
  const int t = threadIdx.x, lane = t & 63, wid = t >> 6;
  const int wr = wid >> 1, wc = wid & 1;
  const float scale = 0.04419417382415922f;  // 512^-0.5

  const u16* Ab = Kb + ((size_t)n * 512 + cy * 128) * 4096;
  const u16* Bb = Qb + ((size_t)n * 512 + dx * 128) * 4096;
  const int srow = t >> 3, scol = (t & 7) << 3;  // staging: chunk=t covers rows 0..31
  f32x4 acc[4][4] = {};

  for (int k0 = 0; k0 < 4096; k0 += 64) {
#pragma unroll
    for (int p = 0; p < 4; ++p) {
      const int row = srow + p * 32;
      u16* ldst_a = &sA[(p * 256 + (wid << 6)) * 8];
      u16* ldst_b = &sB[(p * 256 + (wid << 6)) * 8];
      gld_lds16(Ab + (size_t)row * 4096 + k0 + scol, ldst_a);
      gld_lds16(Bb + (size_t)row * 4096 + k0 + scol, ldst_b);
    }
    __syncthreads();
#pragma unroll
    for (int ki = 0; ki < 2; ++ki) {
      bf16x8 a[4], b[4];
#pragma unroll
      for (int mi = 0; mi < 4; ++mi)
        a[mi] = *(const bf16x8*)&sA[(wr * 64 + mi * 16 + (lane & 15)) * 64 + ki * 32 + (lane >> 4) * 8];
#pragma unroll
      for (int ni = 0; ni < 4; ++ni)
        b[ni] = *(const bf16x8*)&sB[(wc * 64 + ni * 16 + (lane & 15)) * 64 + ki * 32 + (lane >> 4) * 8];
#pragma unroll
      for (int mi = 0; mi < 4; ++mi)
#pragma unroll
        for (int ni = 0; ni < 4; ++ni)
          acc[mi][ni] = __builtin_amdgcn_mfma_f32_16x16x32_bf16(a[mi], b[ni], acc[mi][ni], 0, 0, 0);
    }
    __syncthreads();
  }
  float* Lb = L + (size_t)n * 512 * 512;
  const int c0 = cy * 128, d0 = dx * 128;
#pragma unroll
  for (int mi = 0; mi < 4; ++mi)
#pragma unroll
    for (int ni = 0; ni < 4; ++ni) {
      int colo = d0 + wc * 64 + ni * 16 + (lane & 15);
#pragma unroll
      for (int j = 0; j < 4; ++j) {
        int rowo = c0 + wr * 64 + mi * 16 + ((lane >> 4) << 2) + j;
        Lb[(size_t)rowo * 512 + colo] = acc[mi][ni][j] * scale;
      }
    }
}

// ---------------------------------------------------------------------------
// k_sim (R1 fallback, fp32 inputs): L = scale * K.Q^T, 128x64 tile
// ---------------------------------------------------------------------------
__global__ __launch_bounds__(256) void k_sim(const float* __restrict__ K,
                                             const float* __restrict__ Q,
                                             float* __restrict__ L) {
  __shared__ u16 sA[128 * 64];
  __shared__ u16 sB[64 * 64];
  const int n = blockIdx.z;
  const int c0 = blockIdx.y * 128;
  const int d0 = blockIdx.x * 64;
  const int t = threadIdx.x;
  const int lane = t & 63, wid = t >> 6;
  const int wr = wid >> 1, wc = wid & 1;
  const float scale = 0.04419417382415922f;

  f32x4 acc[4][2] = {};
  const float* Kb = K + ((size_t)n * 512 + c0) * 4096;
  const float* Qb = Q + ((size_t)n * 512 + d0) * 4096;

  for (int k0 = 0; k0 < 4096; k0 += 64) {
#pragma unroll
    for (int p = 0; p < 4; ++p) {
      int chunk = p * 256 + t;
      int row = chunk >> 3, col = (chunk & 7) << 3;
      const float* src = Kb + (size_t)row * 4096 + k0 + col;
      float4 v0 = *(const float4*)src;
      float4 v1 = *(const float4*)(src + 4);
      bf16x8 h;
      h[0] = (__bf16)v0.x; h[1] = (__bf16)v0.y; h[2] = (__bf16)v0.z; h[3] = (__bf16)v0.w;
      h[4] = (__bf16)v1.x; h[5] = (__bf16)v1.y; h[6] = (__bf16)v1.z; h[7] = (__bf16)v1.w;
      int hw = (row * 64 + col) ^ ((row & 7) << 3);
      *(bf16x8*)(&sA[hw]) = h;
    }
#pragma unroll
    for (int p = 0; p < 2; ++p) {
      int chunk = p * 256 + t;
      int row = chunk >> 3, col = (chunk & 7) << 3;
      const float* src = Qb + (size_t)row * 4096 + k0 + col;
      float4 v0 = *(const float4*)src;
      float4 v1 = *(const float4*)(src + 4);
      bf16x8 h;
      h[0] = (__bf16)v0.x; h[1] = (__bf16)v0.y; h[2] = (__bf16)v0.z; h[3] = (__bf16)v0.w;
      h[4] = (__bf16)v1.x; h[5] = (__bf16)v1.y; h[6] = (__bf16)v1.z; h[7] = (__bf16)v1.w;
      int hw = (row * 64 + col) ^ ((row & 7) << 3);
      *(bf16x8*)(&sB[hw]) = h;
    }
    __syncthreads();
#pragma unroll
    for (int ki = 0; ki < 2; ++ki) {
      bf16x8 a[4], b[2];
#pragma unroll
      for (int mi = 0; mi < 4; ++mi) {
        int row = wr * 64 + mi * 16 + (lane & 15);
        int hw = (row * 64 + ki * 32 + (lane >> 4) * 8) ^ ((row & 7) << 3);
        a[mi] = *(const bf16x8*)(&sA[hw]);
      }
#pragma unroll
      for (int ni = 0; ni < 2; ++ni) {
        int row = wc * 32 + ni * 16 + (lane & 15);
        int hw = (row * 64 + ki * 32 + (lane >> 4) * 8) ^ ((row & 7) << 3);
        b[ni] = *(const bf16x8*)(&sB[hw]);
      }
#pragma unroll
      for (int mi = 0; mi < 4; ++mi)
#pragma unroll
        for (int ni = 0; ni < 2; ++ni)
          acc[mi][ni] = __builtin_amdgcn_mfma_f32_16x16x32_bf16(a[mi], b[ni], acc[mi][ni], 0, 0, 0);
    }
    __syncthreads();
  }
  float* Lb = L + (size_t)n * 512 * 512;
#pragma unroll
  for (int mi = 0; mi < 4; ++mi)
#pragma unroll
    for (int ni = 0; ni < 2; ++ni) {
      int colo = d0 + wc * 32 + ni * 16 + (lane & 15);
#pragma unroll
      for (int j = 0; j < 4; ++j) {
        int rowo = c0 + wr * 64 + mi * 16 + ((lane >> 4) << 2) + j;
        Lb[(size_t)rowo * 512 + colo] = acc[mi][ni][j] * scale;
      }
    }
}

// ---------------------------------------------------------------------------
// k_stats: per (n,d) softmax over c; E = exp(L-m)/s in bf16
// ---------------------------------------------------------------------------
__global__ __launch_bounds__(256) void k_stats(const float* __restrict__ L,
                                               u16* __restrict__ E) {
  const int n = blockIdx.y;
  const int d = blockIdx.x * 256 + threadIdx.x;
  const float* Lb = L + (size_t)n * 512 * 512 + d;
  float m = -3.0e38f;
  for (int c = 0; c < 512; ++c) m = fmaxf(m, Lb[(size_t)c * 512]);
  float s = 0.f;
  for (int c = 0; c < 512; ++c) s += __expf(Lb[(size_t)c * 512] - m);
  float si = 1.0f / s;
  u16* Eb = E + (size_t)n * 512 * 512 + d;
  for (int c = 0; c < 512; ++c)
    Eb[(size_t)c * 512] = f2bf(__expf(Lb[(size_t)c * 512] - m) * si);
}

// ---------------------------------------------------------------------------
// k_vt: Vt[n,s,d] = bf16(V[n,d,s])
// ---------------------------------------------------------------------------
__global__ __launch_bounds__(256) void k_vt(const float* __restrict__ V,
                                            u16* __restrict__ Vt) {
  __shared__ float ldsT[64 * 68];
  const int n = blockIdx.z, d0 = blockIdx.y * 64, s0 = blockIdx.x * 64;
  const int t = threadIdx.x;
  {
    int c4 = t & 15, r0 = t >> 4;
#pragma unroll
    for (int p = 0; p < 4; ++p) {
      int r = r0 + p * 16;
      float4 v = *(const float4*)(V + ((size_t)n * 512 + d0 + r) * 4096 + s0 + c4 * 4);
      *(float4*)(&ldsT[r * 68 + c4 * 4]) = v;
    }
  }
  __syncthreads();
  {
    int sr = t >> 2, part = t & 3;
    u16x8 u0, u1;
#pragma unroll
    for (int i = 0; i < 8; ++i) u0[i] = f2bf(ldsT[(part * 16 + i) * 68 + sr]);
#pragma unroll
    for (int i = 0; i < 8; ++i) u1[i] = f2bf(ldsT[(part * 16 + 8 + i) * 68 + sr]);
    u16* dst = Vt + ((size_t)n * 4096 + s0 + sr) * 512 + d0 + part * 16;
    *(u16x8*)dst = u0;
    *(u16x8*)(dst + 8) = u1;
  }
}

// ---------------------------------------------------------------------------
// k_ctx2: out[n,c,s] = sum_d E[n,c,d]*Vt[n,s,d]
// m97 structure: 128x128 tile, BK=64 (8 K-steps), global_load_lds staging.
// grid 2048 linear w/ XCD swizzle (2 batches per XCD).
// ---------------------------------------------------------------------------
__global__ __launch_bounds__(256) void k_ctx2(const u16* __restrict__ E,
                                              const u16* __restrict__ Vt,
                                              float* __restrict__ O) {
  __shared__ u16 sA[128 * 64];
  __shared__ u16 sB[128 * 64];
  const int bid = blockIdx.x;
  const int sid = (bid & 7) * 256 + (bid >> 3);  // 2048 % 8 == 0, bijective
  const int n = sid >> 7;
  const int rem = sid & 127;
  const int cy = rem >> 5, sx = rem & 31;
  const int t = threadIdx.x, lane = t & 63, wid = t >> 6;
  const int wr = wid >> 1, wc = wid & 1;

  const u16* Ab = E + ((size_t)n * 512 + cy * 128) * 512;
  const u16* Bb = Vt + ((size_t)n * 4096 + sx * 128) * 512;
  const int srow = t >> 3, scol = (t & 7) << 3;
  f32x4 acc[4][4] = {};

  for (int kd = 0; kd < 512; kd += 64) {
#pragma unroll
    for (int p = 0; p < 4; ++p) {
      const int row = srow + p * 32;
      gld_lds16(Ab + (size_t)row * 512 + kd + scol, &sA[(p * 256 + (wid << 6)) * 8]);
      gld_lds16(Bb + (size_t)row * 512 + kd + scol, &sB[(p * 256 + (wid << 6)) * 8]);
    }
    __syncthreads();
#pragma unroll
    for (int ki = 0; ki < 2; ++ki) {
      bf16x8 a[4], b[4];
#pragma unroll
      for (int mi = 0; mi < 4; ++mi)
        a[mi] = *(const bf16x8*)&sA[(wr * 64 + mi * 16 + (lane & 15)) * 64 + ki * 32 + (lane >> 4) * 8];
#pragma unroll
      for (int ni = 0; ni < 4; ++ni)
        b[ni] = *(const bf16x8*)&sB[(wc * 64 + ni * 16 + (lane & 15)) * 64 + ki * 32 + (lane >> 4) * 8];
#pragma unroll
      for (int mi = 0; mi < 4; ++mi)
#pragma unroll
        for (int ni = 0; ni < 4; ++ni)
          acc[mi][ni] = __builtin_amdgcn_mfma_f32_16x16x32_bf16(a[mi], b[ni], acc[mi][ni], 0, 0, 0);
    }
    __syncthreads();
  }
  float* Ob = O + ((size_t)n * 512 + cy * 128) * 4096 + sx * 128;
#pragma unroll
  for (int mi = 0; mi < 4; ++mi)
#pragma unroll
    for (int ni = 0; ni < 4; ++ni) {
      int colo = wc * 64 + ni * 16 + (lane & 15);
#pragma unroll
      for (int j = 0; j < 4; ++j) {
        int rowo = wr * 64 + mi * 16 + ((lane >> 4) << 2) + j;
        Ob[(size_t)rowo * 4096 + colo] = acc[mi][ni][j];
      }
    }
}

extern "C" void kernel_launch(void* const* d_in, const int* in_sizes, int n_in,
                              void* d_out, int out_size, void* d_ws, size_t ws_size,
                              hipStream_t stream) {
  const float* Kp = (const float*)d_in[0];  // key
  const float* Vp = (const float*)d_in[1];  // value
  const float* Qp = (const float*)d_in[2];  // query
  float* Op = (float*)d_out;
  char* ws = (char*)d_ws;

  const size_t MB = 1024 * 1024;
  const size_t NEW_NEED = 144 * MB;  // [Kb64|Vt64][Qb64|E8][L16]
  const size_t OLD_NEED = 88 * MB;   // [L16][E8][Vt64]

  if (ws_size >= NEW_NEED) {
    u16* Kb = (u16*)ws;                 // 64 MB, dead after k_sim2
    u16* Qb = (u16*)(ws + 64 * MB);     // 64 MB, dead after k_sim2
    float* L = (float*)(ws + 128 * MB); // 16 MB
    u16* Vt = (u16*)ws;                 // aliases Kb
    u16* E  = (u16*)(ws + 64 * MB);     // aliases Qb

    k_cvt<<<dim3(1024, 2), 256, 0, stream>>>(Kp, Qp, Kb, Qb);
    k_sim2<<<256, 256, 0, stream>>>(Kb, Qb, L);
    k_stats<<<dim3(2, 16), 256, 0, stream>>>(L, E);
    k_vt<<<dim3(64, 8, 16), 256, 0, stream>>>(Vp, Vt);
    k_ctx2<<<2048, 256, 0, stream>>>(E, Vt, Op);
  } else if (ws_size >= OLD_NEED) {
    float* L = (float*)ws;
    u16* E = (u16*)(ws + 16 * MB);
    u16* Vt = (u16*)(ws + 24 * MB);

    k_sim<<<dim3(8, 4, 16), 256, 0, stream>>>(Kp, Qp, L);
    k_stats<<<dim3(2, 16), 256, 0, stream>>>(L, E);
    k_vt<<<dim3(64, 8, 16), 256, 0, stream>>>(Vp, Vt);
    k_ctx2<<<2048, 256, 0, stream>>>(E, Vt, Op);
  }
}

// Round 3
// 315.948 us; speedup vs baseline: 1.3224x; 1.2632x over previous
//
#include <hip/hip_runtime.h>

typedef __bf16 bf16x8 __attribute__((ext_vector_type(8)));
typedef float f32x4 __attribute__((ext_vector_type(4)));
typedef unsigned short u16;
typedef u16 u16x8 __attribute__((ext_vector_type(8)));

__device__ __forceinline__ u16 f2bf(float f) {
  unsigned u = __builtin_bit_cast(unsigned, f);
  unsigned r = (u + 0x7fffu + ((u >> 16) & 1u)) >> 16;  // RNE
  return (u16)r;
}

// async global->LDS, 16B per lane. LDS dest is wave-uniform base + lane*16 (HW).
// Global source address IS per-lane -> swizzled LDS layouts via pre-swizzled src.
__device__ __forceinline__ void gld_lds16(const u16* g, u16* l) {
  __builtin_amdgcn_global_load_lds(
      (__attribute__((address_space(1))) void*)(g),
      (__attribute__((address_space(3))) void*)(l), 16, 0, 0);
}

// ---------------------------------------------------------------------------
// k_cvt: fp32 -> bf16 straight cast for K (y=0) and Q (y=1).
// ---------------------------------------------------------------------------
__global__ __launch_bounds__(256) void k_cvt(const float* __restrict__ K,
                                             const float* __restrict__ Q,
                                             u16* __restrict__ Kb,
                                             u16* __restrict__ Qb) {
  const float* src = blockIdx.y ? Q : K;
  u16* dst = blockIdx.y ? Qb : Kb;
  const size_t total = (size_t)16 * 512 * 4096;
  size_t i = ((size_t)blockIdx.x * 256 + threadIdx.x) * 8;
  const size_t stride = (size_t)gridDim.x * 256 * 8;
  for (; i < total; i += stride) {
    float4 a = *(const float4*)(src + i);
    float4 b = *(const float4*)(src + i + 4);
    u16x8 h;
    h[0] = f2bf(a.x); h[1] = f2bf(a.y); h[2] = f2bf(a.z); h[3] = f2bf(a.w);
    h[4] = f2bf(b.x); h[5] = f2bf(b.y); h[6] = f2bf(b.z); h[7] = f2bf(b.w);
    *(u16x8*)(dst + i) = h;
  }
}

// ---------------------------------------------------------------------------
// k_sim2: L[n,c,d] = scale * sum_s Kb[n,c,s]*Qb[n,d,s]
// 128x128 tile, BK=64, 512 thr / 8 waves (2x4, wave tile 64x32).
// Double-buffered LDS, prefetch-next (T3 minimum), XOR-swizzled layout via
// pre-swizzled global source (linear gld_lds dest) + swizzled ds_read.
// ---------------------------------------------------------------------------
__global__ __launch_bounds__(512) void k_sim2(const u16* __restrict__ Kb,
                                              const u16* __restrict__ Qb,
                                              float* __restrict__ L) {
  __shared__ u16 sA[2][128 * 64];
  __shared__ u16 sB[2][128 * 64];
  const int bid = blockIdx.x;
  const int sid = (bid & 7) * 32 + (bid >> 3);  // 256 % 8 == 0: bijective XCD swizzle
  const int n = sid >> 4;
  const int cy = (sid >> 2) & 3, dx = sid & 3;
  const int t = threadIdx.x, lane = t & 63, wid = t >> 6;
  const int wr = wid >> 2, wc = wid & 3;  // 2x4 waves, wave tile 64x32
  const float scale = 0.04419417382415922f;  // 512^-0.5

  const u16* Ab = Kb + ((size_t)n * 512 + cy * 128) * 4096;
  const u16* Bb = Qb + ((size_t)n * 512 + dx * 128) * 4096;
  f32x4 acc[4][2] = {};

  // staging geometry: chunk = q*512 + t; LDS row = chunk>>3, col16 = t&7.
  const int srow0 = t >> 3;                 // + q*64
  const int ssw = ((srow0 & 7) << 3);       // row-XOR (elements), q*64 keeps row&7
  const int scol = ((t & 7) << 3) ^ ssw;    // pre-swizzled source column

#define SIM_STAGE(buf, k0)                                                      \
  {                                                                             \
    _Pragma("unroll") for (int q = 0; q < 2; ++q) {                             \
      const int row = q * 64 + srow0;                                           \
      gld_lds16(Ab + (size_t)row * 4096 + (k0) + scol,                          \
                &sA[buf][(q * 512 + (wid << 6)) * 8]);                          \
      gld_lds16(Bb + (size_t)row * 4096 + (k0) + scol,                          \
                &sB[buf][(q * 512 + (wid << 6)) * 8]);                          \
    }                                                                           \
  }

#define SIM_COMPUTE(buf)                                                        \
  {                                                                             \
    _Pragma("unroll") for (int ki = 0; ki < 2; ++ki) {                          \
      bf16x8 a[4], b[2];                                                        \
      const int ce = ki * 32 + (lane >> 4) * 8;                                 \
      _Pragma("unroll") for (int mi = 0; mi < 4; ++mi) {                        \
        const int r = wr * 64 + mi * 16 + (lane & 15);                          \
        a[mi] = *(const bf16x8*)&sA[buf][r * 64 + (ce ^ ((r & 7) << 3))];       \
      }                                                                         \
      _Pragma("unroll") for (int ni = 0; ni < 2; ++ni) {                        \
        const int r = wc * 32 + ni * 16 + (lane & 15);                          \
        b[ni] = *(const bf16x8*)&sB[buf][r * 64 + (ce ^ ((r & 7) << 3))];       \
      }                                                                         \
      _Pragma("unroll") for (int mi = 0; mi < 4; ++mi)                          \
        _Pragma("unroll") for (int ni = 0; ni < 2; ++ni)                        \
          acc[mi][ni] = __builtin_amdgcn_mfma_f32_16x16x32_bf16(                \
              a[mi], b[ni], acc[mi][ni], 0, 0, 0);                              \
    }                                                                           \
  }

  SIM_STAGE(0, 0);
  __syncthreads();
  int cur = 0;
  for (int kt = 0; kt < 63; ++kt) {
    SIM_STAGE(cur ^ 1, (kt + 1) << 6);  // prefetch next tile (in flight across compute)
    SIM_COMPUTE(cur);
    __syncthreads();  // drains vmcnt+lgkmcnt: next buffer ready, cur free to overwrite
    cur ^= 1;
  }
  SIM_COMPUTE(cur);

  float* Lb = L + (size_t)n * 512 * 512;
  const int c0 = cy * 128, d0 = dx * 128;
#pragma unroll
  for (int mi = 0; mi < 4; ++mi)
#pragma unroll
    for (int ni = 0; ni < 2; ++ni) {
      int colo = d0 + wc * 32 + ni * 16 + (lane & 15);
#pragma unroll
      for (int j = 0; j < 4; ++j) {
        int rowo = c0 + wr * 64 + mi * 16 + ((lane >> 4) << 2) + j;
        Lb[(size_t)rowo * 512 + colo] = acc[mi][ni][j] * scale;
      }
    }
#undef SIM_STAGE
#undef SIM_COMPUTE
}

// ---------------------------------------------------------------------------
// k_sim (fallback, fp32 inputs, reg-staged): L = scale * K.Q^T, 128x64 tile
// ---------------------------------------------------------------------------
__global__ __launch_bounds__(256) void k_sim(const float* __restrict__ K,
                                             const float* __restrict__ Q,
                                             float* __restrict__ L) {
  __shared__ u16 sA[128 * 64];
  __shared__ u16 sB[64 * 64];
  const int n = blockIdx.z;
  const int c0 = blockIdx.y * 128;
  const int d0 = blockIdx.x * 64;
  const int t = threadIdx.x;
  const int lane = t & 63, wid = t >> 6;
  const int wr = wid >> 1, wc = wid & 1;
  const float scale = 0.04419417382415922f;

  f32x4 acc[4][2] = {};
  const float* Kb = K + ((size_t)n * 512 + c0) * 4096;
  const float* Qb = Q + ((size_t)n * 512 + d0) * 4096;

  for (int k0 = 0; k0 < 4096; k0 += 64) {
#pragma unroll
    for (int p = 0; p < 4; ++p) {
      int chunk = p * 256 + t;
      int row = chunk >> 3, col = (chunk & 7) << 3;
      const float* src = Kb + (size_t)row * 4096 + k0 + col;
      float4 v0 = *(const float4*)src;
      float4 v1 = *(const float4*)(src + 4);
      bf16x8 h;
      h[0] = (__bf16)v0.x; h[1] = (__bf16)v0.y; h[2] = (__bf16)v0.z; h[3] = (__bf16)v0.w;
      h[4] = (__bf16)v1.x; h[5] = (__bf16)v1.y; h[6] = (__bf16)v1.z; h[7] = (__bf16)v1.w;
      int hw = (row * 64 + col) ^ ((row & 7) << 3);
      *(bf16x8*)(&sA[hw]) = h;
    }
#pragma unroll
    for (int p = 0; p < 2; ++p) {
      int chunk = p * 256 + t;
      int row = chunk >> 3, col = (chunk & 7) << 3;
      const float* src = Qb + (size_t)row * 4096 + k0 + col;
      float4 v0 = *(const float4*)src;
      float4 v1 = *(const float4*)(src + 4);
      bf16x8 h;
      h[0] = (__bf16)v0.x; h[1] = (__bf16)v0.y; h[2] = (__bf16)v0.z; h[3] = (__bf16)v0.w;
      h[4] = (__bf16)v1.x; h[5] = (__bf16)v1.y; h[6] = (__bf16)v1.z; h[7] = (__bf16)v1.w;
      int hw = (row * 64 + col) ^ ((row & 7) << 3);
      *(bf16x8*)(&sB[hw]) = h;
    }
    __syncthreads();
#pragma unroll
    for (int ki = 0; ki < 2; ++ki) {
      bf16x8 a[4], b[2];
#pragma unroll
      for (int mi = 0; mi < 4; ++mi) {
        int row = wr * 64 + mi * 16 + (lane & 15);
        int hw = (row * 64 + ki * 32 + (lane >> 4) * 8) ^ ((row & 7) << 3);
        a[mi] = *(const bf16x8*)(&sA[hw]);
      }
#pragma unroll
      for (int ni = 0; ni < 2; ++ni) {
        int row = wc * 32 + ni * 16 + (lane & 15);
        int hw = (row * 64 + ki * 32 + (lane >> 4) * 8) ^ ((row & 7) << 3);
        b[ni] = *(const bf16x8*)(&sB[hw]);
      }
#pragma unroll
      for (int mi = 0; mi < 4; ++mi)
#pragma unroll
        for (int ni = 0; ni < 2; ++ni)
          acc[mi][ni] = __builtin_amdgcn_mfma_f32_16x16x32_bf16(a[mi], b[ni], acc[mi][ni], 0, 0, 0);
    }
    __syncthreads();
  }
  float* Lb = L + (size_t)n * 512 * 512;
#pragma unroll
  for (int mi = 0; mi < 4; ++mi)
#pragma unroll
    for (int ni = 0; ni < 2; ++ni) {
      int colo = d0 + wc * 32 + ni * 16 + (lane & 15);
#pragma unroll
      for (int j = 0; j < 4; ++j) {
        int rowo = c0 + wr * 64 + mi * 16 + ((lane >> 4) << 2) + j;
        Lb[(size_t)rowo * 512 + colo] = acc[mi][ni][j] * scale;
      }
    }
}

// ---------------------------------------------------------------------------
// k_stats: per (n,d) softmax over c. Block = (n, 64 d's); 4 c-stripes/wave.
// ---------------------------------------------------------------------------
__global__ __launch_bounds__(256) void k_stats(const float* __restrict__ L,
                                               u16* __restrict__ E) {
  __shared__ float red[4][64];
  const int n = blockIdx.y;
  const int d0 = blockIdx.x * 64;
  const int tx = threadIdx.x & 63, ty = threadIdx.x >> 6;
  const float* Lb = L + (size_t)n * 512 * 512 + d0 + tx;

  float m = -3.0e38f;
  for (int c = ty; c < 512; c += 4) m = fmaxf(m, Lb[(size_t)c * 512]);
  red[ty][tx] = m;
  __syncthreads();
  m = fmaxf(fmaxf(red[0][tx], red[1][tx]), fmaxf(red[2][tx], red[3][tx]));
  __syncthreads();

  float s = 0.f;
  for (int c = ty; c < 512; c += 4) s += __expf(Lb[(size_t)c * 512] - m);
  red[ty][tx] = s;
  __syncthreads();
  s = red[0][tx] + red[1][tx] + red[2][tx] + red[3][tx];
  const float si = 1.0f / s;

  u16* Eb = E + (size_t)n * 512 * 512 + d0 + tx;
  for (int c = ty; c < 512; c += 4)
    Eb[(size_t)c * 512] = f2bf(__expf(Lb[(size_t)c * 512] - m) * si);
}

// ---------------------------------------------------------------------------
// k_vt: Vt[n,s,d] = bf16(V[n,d,s])
// ---------------------------------------------------------------------------
__global__ __launch_bounds__(256) void k_vt(const float* __restrict__ V,
                                            u16* __restrict__ Vt) {
  __shared__ float ldsT[64 * 68];
  const int n = blockIdx.z, d0 = blockIdx.y * 64, s0 = blockIdx.x * 64;
  const int t = threadIdx.x;
  {
    int c4 = t & 15, r0 = t >> 4;
#pragma unroll
    for (int p = 0; p < 4; ++p) {
      int r = r0 + p * 16;
      float4 v = *(const float4*)(V + ((size_t)n * 512 + d0 + r) * 4096 + s0 + c4 * 4);
      *(float4*)(&ldsT[r * 68 + c4 * 4]) = v;
    }
  }
  __syncthreads();
  {
    int sr = t >> 2, part = t & 3;
    u16x8 u0, u1;
#pragma unroll
    for (int i = 0; i < 8; ++i) u0[i] = f2bf(ldsT[(part * 16 + i) * 68 + sr]);
#pragma unroll
    for (int i = 0; i < 8; ++i) u1[i] = f2bf(ldsT[(part * 16 + 8 + i) * 68 + sr]);
    u16* dst = Vt + ((size_t)n * 4096 + s0 + sr) * 512 + d0 + part * 16;
    *(u16x8*)dst = u0;
    *(u16x8*)(dst + 8) = u1;
  }
}

// ---------------------------------------------------------------------------
// k_ctx2: out[n,c,s] = sum_d E[n,c,d]*Vt[n,s,d]
// 128x128 tile, BK=64 (8 K-steps), single-buffer (5 blocks/CU TLP), swizzled.
// ---------------------------------------------------------------------------
__global__ __launch_bounds__(256) void k_ctx2(const u16* __restrict__ E,
                                              const u16* __restrict__ Vt,
                                              float* __restrict__ O) {
  __shared__ u16 sA[128 * 64];
  __shared__ u16 sB[128 * 64];
  const int bid = blockIdx.x;
  const int sid = (bid & 7) * 256 + (bid >> 3);  // 2048 % 8 == 0, bijective
  const int n = sid >> 7;
  const int rem = sid & 127;
  const int cy = rem >> 5, sx = rem & 31;
  const int t = threadIdx.x, lane = t & 63, wid = t >> 6;
  const int wr = wid >> 1, wc = wid & 1;

  const u16* Ab = E + ((size_t)n * 512 + cy * 128) * 512;
  const u16* Bb = Vt + ((size_t)n * 4096 + sx * 128) * 512;
  const int srow0 = t >> 3;                         // + p*32 (p*32 % 8 == 0)
  const int scol = ((t & 7) << 3) ^ ((srow0 & 7) << 3);
  f32x4 acc[4][4] = {};

  for (int kd = 0; kd < 512; kd += 64) {
#pragma unroll
    for (int p = 0; p < 4; ++p) {
      const int row = srow0 + p * 32;
      gld_lds16(Ab + (size_t)row * 512 + kd + scol, &sA[(p * 256 + (wid << 6)) * 8]);
      gld_lds16(Bb + (size_t)row * 512 + kd + scol, &sB[(p * 256 + (wid << 6)) * 8]);
    }
    __syncthreads();
#pragma unroll
    for (int ki = 0; ki < 2; ++ki) {
      bf16x8 a[4], b[4];
      const int ce = ki * 32 + (lane >> 4) * 8;
#pragma unroll
      for (int mi = 0; mi < 4; ++mi) {
        const int r = wr * 64 + mi * 16 + (lane & 15);
        a[mi] = *(const bf16x8*)&sA[r * 64 + (ce ^ ((r & 7) << 3))];
      }
#pragma unroll
      for (int ni = 0; ni < 4; ++ni) {
        const int r = wc * 64 + ni * 16 + (lane & 15);
        b[ni] = *(const bf16x8*)&sB[r * 64 + (ce ^ ((r & 7) << 3))];
      }
#pragma unroll
      for (int mi = 0; mi < 4; ++mi)
#pragma unroll
        for (int ni = 0; ni < 4; ++ni)
          acc[mi][ni] = __builtin_amdgcn_mfma_f32_16x16x32_bf16(a[mi], b[ni], acc[mi][ni], 0, 0, 0);
    }
    __syncthreads();
  }
  float* Ob = O + ((size_t)n * 512 + cy * 128) * 4096 + sx * 128;
#pragma unroll
  for (int mi = 0; mi < 4; ++mi)
#pragma unroll
    for (int ni = 0; ni < 4; ++ni) {
      int colo = wc * 64 + ni * 16 + (lane & 15);
#pragma unroll
      for (int j = 0; j < 4; ++j) {
        int rowo = wr * 64 + mi * 16 + ((lane >> 4) << 2) + j;
        Ob[(size_t)rowo * 4096 + colo] = acc[mi][ni][j];
      }
    }
}

extern "C" void kernel_launch(void* const* d_in, const int* in_sizes, int n_in,
                              void* d_out, int out_size, void* d_ws, size_t ws_size,
                              hipStream_t stream) {
  const float* Kp = (const float*)d_in[0];  // key
  const float* Vp = (const float*)d_in[1];  // value
  const float* Qp = (const float*)d_in[2];  // query
  float* Op = (float*)d_out;
  char* ws = (char*)d_ws;

  const size_t MB = 1024 * 1024;
  const size_t NEW_NEED = 144 * MB;  // [Kb64|Vt64][Qb64|E8][L16]
  const size_t OLD_NEED = 88 * MB;   // [L16][E8][Vt64]

  if (ws_size >= NEW_NEED) {
    u16* Kb = (u16*)ws;                 // 64 MB, dead after k_sim2
    u16* Qb = (u16*)(ws + 64 * MB);     // 64 MB, dead after k_sim2
    float* L = (float*)(ws + 128 * MB); // 16 MB
    u16* Vt = (u16*)ws;                 // aliases Kb
    u16* E  = (u16*)(ws + 64 * MB);     // aliases Qb

    k_cvt<<<dim3(1024, 2), 256, 0, stream>>>(Kp, Qp, Kb, Qb);
    k_sim2<<<256, 512, 0, stream>>>(Kb, Qb, L);
    k_stats<<<dim3(8, 16), 256, 0, stream>>>(L, E);
    k_vt<<<dim3(64, 8, 16), 256, 0, stream>>>(Vp, Vt);
    k_ctx2<<<2048, 256, 0, stream>>>(E, Vt, Op);
  } else if (ws_size >= OLD_NEED) {
    float* L = (float*)ws;
    u16* E = (u16*)(ws + 16 * MB);
    u16* Vt = (u16*)(ws + 24 * MB);

    k_sim<<<dim3(8, 4, 16), 256, 0, stream>>>(Kp, Qp, L);
    k_stats<<<dim3(8, 16), 256, 0, stream>>>(L, E);
    k_vt<<<dim3(64, 8, 16), 256, 0, stream>>>(Vp, Vt);
    k_ctx2<<<2048, 256, 0, stream>>>(E, Vt, Op);
  }
}

// Round 4
// 295.984 us; speedup vs baseline: 1.4116x; 1.0674x over previous
//
#include <hip/hip_runtime.h>

typedef __bf16 bf16x8 __attribute__((ext_vector_type(8)));
typedef float f32x4 __attribute__((ext_vector_type(4)));
typedef unsigned short u16;
typedef u16 u16x8 __attribute__((ext_vector_type(8)));

__device__ __forceinline__ u16 f2bf(float f) {
  unsigned u = __builtin_bit_cast(unsigned, f);
  unsigned r = (u + 0x7fffu + ((u >> 16) & 1u)) >> 16;  // RNE
  return (u16)r;
}

__device__ __forceinline__ bf16x8 cvt8(float4 a, float4 b) {
  bf16x8 h;
  h[0] = (__bf16)a.x; h[1] = (__bf16)a.y; h[2] = (__bf16)a.z; h[3] = (__bf16)a.w;
  h[4] = (__bf16)b.x; h[5] = (__bf16)b.y; h[6] = (__bf16)b.z; h[7] = (__bf16)b.w;
  return h;  // compiler lowers to v_cvt_pk_bf16_f32 (RNE)
}

// async global->LDS, 16B per lane (dest = wave-uniform base + lane*16 in HW).
__device__ __forceinline__ void gld_lds16(const u16* g, u16* l) {
  __builtin_amdgcn_global_load_lds(
      (__attribute__((address_space(1))) void*)(g),
      (__attribute__((address_space(3))) void*)(l), 16, 0, 0);
}

// ---------------------------------------------------------------------------
// k_simf: L[n,c,d] = scale * sum_s K[n,c,s]*Q[n,d,s]   (fp32 in, fused cvt)
// 128x128 tile, BK=64, 512 thr / 8 waves (2x4, wave tile 64x32).
// Reg-staged: global fp32 -> v_cvt_pk -> swizzled ds_write_b128. Loads for
// tile t+1 issued before compute(t) -> HBM latency hides under MFMA.
// ---------------------------------------------------------------------------
__global__ __launch_bounds__(512) void k_simf(const float* __restrict__ K,
                                              const float* __restrict__ Q,
                                              float* __restrict__ L) {
  __shared__ u16 sA[128 * 64];
  __shared__ u16 sB[128 * 64];
  const int bid = blockIdx.x;
  const int sid = (bid & 7) * 32 + (bid >> 3);  // 256 % 8 == 0: bijective XCD swizzle
  const int n = sid >> 4;
  const int cy = (sid >> 2) & 3, dx = sid & 3;
  const int t = threadIdx.x, lane = t & 63, wid = t >> 6;
  const int wr = wid >> 2, wc = wid & 3;  // 2x4 waves, wave tile 64x32
  const float scale = 0.04419417382415922f;  // 512^-0.5

  const float* Ab = K + ((size_t)n * 512 + cy * 128) * 4096;
  const float* Bb = Q + ((size_t)n * 512 + dx * 128) * 4096;

  // staging geometry: rows r0 = t>>3 and r0+64; col8 = (t&7)*8 (8 fp32/row-visit)
  const int r0 = t >> 3, col8 = (t & 7) << 3;
  const int swz = col8 ^ ((r0 & 7) << 3);  // (r0+64)&7 == r0&7
  u16* const wA0 = &sA[r0 * 64 + swz];
  u16* const wA1 = &sA[(r0 + 64) * 64 + swz];
  u16* const wB0 = &sB[r0 * 64 + swz];
  u16* const wB1 = &sB[(r0 + 64) * 64 + swz];

  float4 ra[4], rb[4];
  f32x4 acc[4][2] = {};

#define SIMF_LOAD(k0)                                                           \
  {                                                                             \
    const float* pa = Ab + (size_t)r0 * 4096 + (k0) + col8;                     \
    ra[0] = *(const float4*)pa;                                                 \
    ra[1] = *(const float4*)(pa + 4);                                           \
    ra[2] = *(const float4*)(pa + 64 * 4096);                                   \
    ra[3] = *(const float4*)(pa + 64 * 4096 + 4);                               \
    const float* pb = Bb + (size_t)r0 * 4096 + (k0) + col8;                     \
    rb[0] = *(const float4*)pb;                                                 \
    rb[1] = *(const float4*)(pb + 4);                                           \
    rb[2] = *(const float4*)(pb + 64 * 4096);                                   \
    rb[3] = *(const float4*)(pb + 64 * 4096 + 4);                               \
  }

#define SIMF_WRITE()                                                            \
  {                                                                             \
    *(bf16x8*)wA0 = cvt8(ra[0], ra[1]);                                         \
    *(bf16x8*)wA1 = cvt8(ra[2], ra[3]);                                         \
    *(bf16x8*)wB0 = cvt8(rb[0], rb[1]);                                         \
    *(bf16x8*)wB1 = cvt8(rb[2], rb[3]);                                         \
  }

#define SIMF_COMPUTE()                                                          \
  {                                                                             \
    _Pragma("unroll") for (int ki = 0; ki < 2; ++ki) {                          \
      bf16x8 a[4], b[2];                                                        \
      const int ce = ki * 32 + (lane >> 4) * 8;                                 \
      _Pragma("unroll") for (int mi = 0; mi < 4; ++mi) {                        \
        const int r = wr * 64 + mi * 16 + (lane & 15);                          \
        a[mi] = *(const bf16x8*)&sA[r * 64 + (ce ^ ((r & 7) << 3))];            \
      }                                                                         \
      _Pragma("unroll") for (int ni = 0; ni < 2; ++ni) {                        \
        const int r = wc * 32 + ni * 16 + (lane & 15);                          \
        b[ni] = *(const bf16x8*)&sB[r * 64 + (ce ^ ((r & 7) << 3))];            \
      }                                                                         \
      _Pragma("unroll") for (int mi = 0; mi < 4; ++mi)                          \
        _Pragma("unroll") for (int ni = 0; ni < 2; ++ni)                        \
          acc[mi][ni] = __builtin_amdgcn_mfma_f32_16x16x32_bf16(                \
              a[mi], b[ni], acc[mi][ni], 0, 0, 0);                              \
    }                                                                           \
  }

  SIMF_LOAD(0);
  for (int kt = 0; kt < 64; ++kt) {
    SIMF_WRITE();       // regs (tile kt) -> LDS
    __syncthreads();    // LDS tile ready
    if (kt < 63) SIMF_LOAD((kt + 1) << 6);  // next tile in flight during MFMA
    SIMF_COMPUTE();
    __syncthreads();    // everyone done reading before next overwrite
  }

  float* Lb = L + (size_t)n * 512 * 512;
  const int c0 = cy * 128, d0 = dx * 128;
#pragma unroll
  for (int mi = 0; mi < 4; ++mi)
#pragma unroll
    for (int ni = 0; ni < 2; ++ni) {
      int colo = d0 + wc * 32 + ni * 16 + (lane & 15);
#pragma unroll
      for (int j = 0; j < 4; ++j) {
        int rowo = c0 + wr * 64 + mi * 16 + ((lane >> 4) << 2) + j;
        Lb[(size_t)rowo * 512 + colo] = acc[mi][ni][j] * scale;
      }
    }
#undef SIMF_LOAD
#undef SIMF_WRITE
#undef SIMF_COMPUTE
}

// ---------------------------------------------------------------------------
// k_stats: per (n,d) softmax over c. Block = (n, 64 d's); 4 c-stripes/wave.
// ---------------------------------------------------------------------------
__global__ __launch_bounds__(256) void k_stats(const float* __restrict__ L,
                                               u16* __restrict__ E) {
  __shared__ float red[4][64];
  const int n = blockIdx.y;
  const int d0 = blockIdx.x * 64;
  const int tx = threadIdx.x & 63, ty = threadIdx.x >> 6;
  const float* Lb = L + (size_t)n * 512 * 512 + d0 + tx;

  float m = -3.0e38f;
  for (int c = ty; c < 512; c += 4) m = fmaxf(m, Lb[(size_t)c * 512]);
  red[ty][tx] = m;
  __syncthreads();
  m = fmaxf(fmaxf(red[0][tx], red[1][tx]), fmaxf(red[2][tx], red[3][tx]));
  __syncthreads();

  float s = 0.f;
  for (int c = ty; c < 512; c += 4) s += __expf(Lb[(size_t)c * 512] - m);
  red[ty][tx] = s;
  __syncthreads();
  s = red[0][tx] + red[1][tx] + red[2][tx] + red[3][tx];
  const float si = 1.0f / s;

  u16* Eb = E + (size_t)n * 512 * 512 + d0 + tx;
  for (int c = ty; c < 512; c += 4)
    Eb[(size_t)c * 512] = f2bf(__expf(Lb[(size_t)c * 512] - m) * si);
}

// ---------------------------------------------------------------------------
// k_vt: Vt[n,s,d] = bf16(V[n,d,s]).  Tile: 128 d x 64 s.
// Reads: 64B-contiguous per lane, 256B per row-segment. Writes: 256B rows.
// LDS fp32 [128][68] with XOR swizzle on col by (d>>3)&7 so the transposed
// column-read (fixed s, d varying by 8s) spreads banks (2-way).
// ---------------------------------------------------------------------------
__global__ __launch_bounds__(256) void k_vt(const float* __restrict__ V,
                                            u16* __restrict__ Vt) {
  __shared__ float lds[128 * 68];
  const int n = blockIdx.z, d0 = blockIdx.y * 128, s0 = blockIdx.x * 64;
  const int t = threadIdx.x;
  {
    const int dr0 = t >> 2, c16 = (t & 3) << 4;  // 4 lanes/row, 16 fp32 each
#pragma unroll
    for (int p = 0; p < 2; ++p) {
      const int dr = dr0 + p * 64;
      const float* src = V + ((size_t)n * 512 + d0 + dr) * 4096 + s0 + c16;
      float4 v0 = *(const float4*)src;
      float4 v1 = *(const float4*)(src + 4);
      float4 v2 = *(const float4*)(src + 8);
      float4 v3 = *(const float4*)(src + 12);
      const int sw = ((dr >> 3) & 7) << 2;
      float* dl = &lds[dr * 68];
      *(float4*)(dl + ((c16 + 0) ^ sw)) = v0;
      *(float4*)(dl + ((c16 + 4) ^ sw)) = v1;
      *(float4*)(dl + ((c16 + 8) ^ sw)) = v2;
      *(float4*)(dl + ((c16 + 12) ^ sw)) = v3;
    }
  }
  __syncthreads();
  {
    const int sr0 = t >> 4, dcol = (t & 15) << 3;  // 16 lanes/row -> 256B rows
#pragma unroll
    for (int p2 = 0; p2 < 4; ++p2) {
      const int sr = sr0 + p2 * 16;
      bf16x8 h;
#pragma unroll
      for (int j = 0; j < 8; ++j) {
        const int d = dcol + j;
        h[j] = (__bf16)lds[d * 68 + (sr ^ (((d >> 3) & 7) << 2))];
      }
      *(bf16x8*)(Vt + ((size_t)n * 4096 + s0 + sr) * 512 + d0 + dcol) = h;
    }
  }
}

// ---------------------------------------------------------------------------
// k_ctx2: out[n,c,s] = sum_d E[n,c,d]*Vt[n,s,d]
// 128x128 tile, BK=64 (8 K-steps), gld_lds staging, pre-swizzled source.
// ---------------------------------------------------------------------------
__global__ __launch_bounds__(256) void k_ctx2(const u16* __restrict__ E,
                                              const u16* __restrict__ Vt,
                                              float* __restrict__ O) {
  __shared__ u16 sA[128 * 64];
  __shared__ u16 sB[128 * 64];
  const int bid = blockIdx.x;
  const int sid = (bid & 7) * 256 + (bid >> 3);  // 2048 % 8 == 0, bijective
  const int n = sid >> 7;
  const int rem = sid & 127;
  const int cy = rem >> 5, sx = rem & 31;
  const int t = threadIdx.x, lane = t & 63, wid = t >> 6;
  const int wr = wid >> 1, wc = wid & 1;

  const u16* Ab = E + ((size_t)n * 512 + cy * 128) * 512;
  const u16* Bb = Vt + ((size_t)n * 4096 + sx * 128) * 512;
  const int srow0 = t >> 3;                         // + p*32 (p*32 % 8 == 0)
  const int scol = ((t & 7) << 3) ^ ((srow0 & 7) << 3);
  f32x4 acc[4][4] = {};

  for (int kd = 0; kd < 512; kd += 64) {
#pragma unroll
    for (int p = 0; p < 4; ++p) {
      const int row = srow0 + p * 32;
      gld_lds16(Ab + (size_t)row * 512 + kd + scol, &sA[(p * 256 + (wid << 6)) * 8]);
      gld_lds16(Bb + (size_t)row * 512 + kd + scol, &sB[(p * 256 + (wid << 6)) * 8]);
    }
    __syncthreads();
#pragma unroll
    for (int ki = 0; ki < 2; ++ki) {
      bf16x8 a[4], b[4];
      const int ce = ki * 32 + (lane >> 4) * 8;
#pragma unroll
      for (int mi = 0; mi < 4; ++mi) {
        const int r = wr * 64 + mi * 16 + (lane & 15);
        a[mi] = *(const bf16x8*)&sA[r * 64 + (ce ^ ((r & 7) << 3))];
      }
#pragma unroll
      for (int ni = 0; ni < 4; ++ni) {
        const int r = wc * 64 + ni * 16 + (lane & 15);
        b[ni] = *(const bf16x8*)&sB[r * 64 + (ce ^ ((r & 7) << 3))];
      }
#pragma unroll
      for (int mi = 0; mi < 4; ++mi)
#pragma unroll
        for (int ni = 0; ni < 4; ++ni)
          acc[mi][ni] = __builtin_amdgcn_mfma_f32_16x16x32_bf16(a[mi], b[ni], acc[mi][ni], 0, 0, 0);
    }
    __syncthreads();
  }
  float* Ob = O + ((size_t)n * 512 + cy * 128) * 4096 + sx * 128;
#pragma unroll
  for (int mi = 0; mi < 4; ++mi)
#pragma unroll
    for (int ni = 0; ni < 4; ++ni) {
      int colo = wc * 64 + ni * 16 + (lane & 15);
#pragma unroll
      for (int j = 0; j < 4; ++j) {
        int rowo = wr * 64 + mi * 16 + ((lane >> 4) << 2) + j;
        Ob[(size_t)rowo * 4096 + colo] = acc[mi][ni][j];
      }
    }
}

extern "C" void kernel_launch(void* const* d_in, const int* in_sizes, int n_in,
                              void* d_out, int out_size, void* d_ws, size_t ws_size,
                              hipStream_t stream) {
  const float* Kp = (const float*)d_in[0];  // key
  const float* Vp = (const float*)d_in[1];  // value
  const float* Qp = (const float*)d_in[2];  // query
  float* Op = (float*)d_out;
  char* ws = (char*)d_ws;

  const size_t MB = 1024 * 1024;
  if (ws_size < 88 * MB) return;
  float* L = (float*)ws;            // 16 MiB
  u16* E = (u16*)(ws + 16 * MB);    //  8 MiB
  u16* Vt = (u16*)(ws + 24 * MB);   // 64 MiB

  k_simf<<<256, 512, 0, stream>>>(Kp, Qp, L);
  k_vt<<<dim3(64, 4, 16), 256, 0, stream>>>(Vp, Vt);
  k_stats<<<dim3(8, 16), 256, 0, stream>>>(L, E);
  k_ctx2<<<2048, 256, 0, stream>>>(E, Vt, Op);
}